// Round 7
// baseline (416.408 us; speedup 1.0000x reference)
//
#include <hip/hip_runtime.h>
#include <math.h>

#define Bn 4
#define Tn 2048
#define En 1024
#define Hn 16
#define Dn 64
#define RS2 (2 * En)
#define QSCALE 0.18033688f   // (1/sqrt(64)) * log2(e)  -> softmax in exp2 domain
#define SMAX 16.0f           // static softmax max (log2 domain); scores bounded << 16

typedef __attribute__((ext_vector_type(8))) short bfrag;   // 8 bf16 in 4 VGPRs
typedef __attribute__((ext_vector_type(4))) float ffrag;   // 4 fp32 acc

__device__ __forceinline__ unsigned short f2bf(float f) {
    union { float f; unsigned int u; } v; v.f = f;
    unsigned int r = v.u + 0x7fffu + ((v.u >> 16) & 1u);   // RNE
    return (unsigned short)(r >> 16);
}
__device__ __forceinline__ unsigned short f2bf_fast(float f) {  // positive, no NaN
    union { float f; unsigned int u; } v; v.f = f;
    return (unsigned short)((v.u + 0x8000u) >> 16);
}

__device__ __forceinline__ void glds16(const unsigned short* g, unsigned short* l) {
    __builtin_amdgcn_global_load_lds(
        (const __attribute__((address_space(1))) unsigned int*)g,
        (__attribute__((address_space(3))) unsigned int*)l, 16, 0, 0);
}

// ---- DPP 16-lane row sum ----
template <int CTRL>
__device__ __forceinline__ float dpp_add_step(float x) {
    int s = __builtin_amdgcn_update_dpp(0, __builtin_bit_cast(int, x), CTRL, 0xF, 0xF, true);
    return x + __builtin_bit_cast(float, s);
}
__device__ __forceinline__ float rowsum16(float x) {
    x = dpp_add_step<0xB1>(x);    // quad_perm xor1
    x = dpp_add_step<0x4E>(x);    // quad_perm xor2
    x = dpp_add_step<0x141>(x);   // row_half_mirror
    x = dpp_add_step<0x140>(x);   // row_mirror
    return x;
}

// ---------------- fp32 -> bf16 elementwise ----------------
__global__ __launch_bounds__(256) void f2bf_vec(const float* __restrict__ in,
                                                unsigned short* __restrict__ out, int n) {
    int i = (blockIdx.x * 256 + threadIdx.x) * 4;
    if (i >= n) return;
    float4 v = *(const float4*)(in + i);
    ushort4 o;
    o.x = f2bf(v.x); o.y = f2bf(v.y); o.z = f2bf(v.z); o.w = f2bf(v.w);
    *(ushort4*)(out + i) = o;
}

// ---------------- W[K][N] fp32 -> Wt[N][K] bf16 ----------------
__global__ __launch_bounds__(256) void transpose_f2bf(const float* __restrict__ W,
                                                      unsigned short* __restrict__ Wt,
                                                      int K, int N) {
    __shared__ float s[64][65];
    const int kt = blockIdx.y * 64, nt = blockIdx.x * 64;
    const int tx = threadIdx.x & 15, ty = threadIdx.x >> 4;
#pragma unroll
    for (int i = 0; i < 4; ++i) {
        float4 v = *(const float4*)&W[(size_t)(kt + ty + i * 16) * N + nt + tx * 4];
        s[ty + i * 16][tx * 4 + 0] = v.x;
        s[ty + i * 16][tx * 4 + 1] = v.y;
        s[ty + i * 16][tx * 4 + 2] = v.z;
        s[ty + i * 16][tx * 4 + 3] = v.w;
    }
    __syncthreads();
#pragma unroll
    for (int i = 0; i < 4; ++i) {
        const int n = ty + i * 16;
        ushort4 o;
        o.x = f2bf(s[tx * 4 + 0][n]);
        o.y = f2bf(s[tx * 4 + 1][n]);
        o.z = f2bf(s[tx * 4 + 2][n]);
        o.w = f2bf(s[tx * 4 + 3][n]);
        *(ushort4*)&Wt[(size_t)(nt + n) * K + kt + tx * 4] = o;
    }
}

// ---------------- NT bf16 MFMA GEMM, LDS-free / barrier-free ----------------
// C = A[M,K] @ Bt[N,K]^T + bias. Block = 4 independent waves, each owning a
// 64x64 tile of the block's 128x128. Frags load straight from global to VGPRs
// (NT layout = native MFMA A/B fragment order); register double-buffer gives
// the compiler a full compute phase of load/use distance, and with no
// __syncthreads the fine-grained vmcnt(N) pipeline survives (no vmcnt(0) drain).
template <int OUT_BF16, int VSPLIT>
__global__ __launch_bounds__(256) void gemm_nt_mfma(
    const unsigned short* __restrict__ A, const unsigned short* __restrict__ Bt,
    const float* __restrict__ bias, void* __restrict__ Cv, int ldc,
    unsigned short* __restrict__ vt, int vstart,
    int M, int N, int K, int qcols)
{
    const int t = threadIdx.x;
    const int w = t >> 6, l = t & 63;
    const int wmt = (w & 1) * 4, wnt = (w >> 1) * 4;
    const int m0 = blockIdx.y * 128, n0 = blockIdx.x * 128;
    const int nl = l & 15, lq = l >> 4;

    ffrag acc[4][4];
#pragma unroll
    for (int i = 0; i < 4; ++i)
#pragma unroll
        for (int j = 0; j < 4; ++j)
#pragma unroll
            for (int r = 0; r < 4; ++r) acc[i][j][r] = 0.f;

    const unsigned short* Ab = A  + (size_t)(m0 + wmt * 16 + nl) * K + lq * 8;
    const unsigned short* Bb = Bt + (size_t)(n0 + wnt * 16 + nl) * K + lq * 8;

    bfrag a0[4], b0[4], a1[4], b1[4];
#pragma unroll
    for (int i = 0; i < 4; ++i) {
        a0[i] = *(const bfrag*)(Ab + (size_t)i * 16 * K);
        b0[i] = *(const bfrag*)(Bb + (size_t)i * 16 * K);
    }

    const int iters = K >> 5;   // 32 (K=1024)
#pragma unroll 1
    for (int it = 0; it < iters; it += 2) {
        const int k1 = (it + 1) << 5;
#pragma unroll
        for (int i = 0; i < 4; ++i) {
            a1[i] = *(const bfrag*)(Ab + (size_t)i * 16 * K + k1);
            b1[i] = *(const bfrag*)(Bb + (size_t)i * 16 * K + k1);
        }
#pragma unroll
        for (int i = 0; i < 4; ++i)
#pragma unroll
            for (int j = 0; j < 4; ++j)
                acc[i][j] = __builtin_amdgcn_mfma_f32_16x16x32_bf16(a0[i], b0[j], acc[i][j], 0, 0, 0);
        const int k2 = (it + 2 < iters) ? ((it + 2) << 5) : k1;
#pragma unroll
        for (int i = 0; i < 4; ++i) {
            a0[i] = *(const bfrag*)(Ab + (size_t)i * 16 * K + k2);
            b0[i] = *(const bfrag*)(Bb + (size_t)i * 16 * K + k2);
        }
#pragma unroll
        for (int i = 0; i < 4; ++i)
#pragma unroll
            for (int j = 0; j < 4; ++j)
                acc[i][j] = __builtin_amdgcn_mfma_f32_16x16x32_bf16(a1[i], b1[j], acc[i][j], 0, 0, 0);
    }

    const int orow = (l >> 4) * 4, ocol = l & 15;
#pragma unroll
    for (int i = 0; i < 4; ++i) {
        const int gm = m0 + (wmt + i) * 16 + orow;
#pragma unroll
        for (int j = 0; j < 4; ++j) {
            const int gn = n0 + (wnt + j) * 16 + ocol;
            const float bs = bias[gn];
            if (VSPLIT && gn >= vstart) {
                const int vc = gn - vstart;
                const int b  = gm / Tn;
                const int tt = gm - b * Tn;
                ushort4 o;
                o.x = f2bf(acc[i][j][0] + bs);
                o.y = f2bf(acc[i][j][1] + bs);
                o.z = f2bf(acc[i][j][2] + bs);
                o.w = f2bf(acc[i][j][3] + bs);
                *(ushort4*)&vt[(size_t)(b * Hn * Dn + vc) * Tn + tt] = o;
            } else {
                const float sc = (qcols && gn < qcols) ? QSCALE : 1.f;
#pragma unroll
                for (int r = 0; r < 4; ++r) {
                    const float vv = (acc[i][j][r] + bs) * sc;
                    if (OUT_BF16)
                        ((unsigned short*)Cv)[(size_t)(gm + r) * ldc + gn] = f2bf(vv);
                    else
                        ((float*)Cv)[(size_t)(gm + r) * ldc + gn] = vv;
                }
            }
        }
    }
}

// ---------------- MFMA flash attention (unchanged from round 5) ----------------
__global__ __launch_bounds__(256) void attn_mfma(
    const unsigned short* __restrict__ qkv,   // [B*T][2E]  Q|K, Q pre-scaled
    const unsigned short* __restrict__ vtg,   // [B*H*D][T] V transposed
    unsigned short* __restrict__ yattn)       // [B*T][E]
{
    __shared__ __attribute__((aligned(16))) unsigned short KT[128 * 64];
    __shared__ __attribute__((aligned(16))) unsigned short VT[64 * 128];
    __shared__ __attribute__((aligned(16))) unsigned short Ps[4][16][136];

    const int t = threadIdx.x;
    const int w = t >> 6, l = t & 63;
    const int nl = l & 15, lq = l >> 4;
    const int flat = blockIdx.x;
    const int bh = flat & 63;
    const int qp = flat >> 6;         // 0..7
    const int b = bh >> 4, h = bh & 15;

    const unsigned short* qbase = qkv + (size_t)(b * Tn) * RS2 + h * Dn;
    const unsigned short* kbase = qbase + En;
    const unsigned short* vbase = vtg + (size_t)(bh * Dn) * Tn;
    unsigned short* yb = yattn + (size_t)(b * Tn) * En + h * Dn;

#pragma unroll 1
    for (int half = 0; half < 2; ++half) {
        const int p = qp + half * 8;          // pair 0..15
#pragma unroll 1
        for (int phase = 0; phase < 2; ++phase) {
            const int qt = phase ? (31 - p) : p;
            const int rowb = qt * 64 + w * 16;
            const int jmax = qt >> 1;

            bfrag qf[2];
#pragma unroll
            for (int ks = 0; ks < 2; ++ks)
                qf[ks] = *(const bfrag*)(qbase + (size_t)(rowb + nl) * RS2 + ks * 32 + lq * 8);

            ffrag Oa[4];
            float l_i[4];
#pragma unroll
            for (int r = 0; r < 4; ++r) {
                l_i[r] = 0.f;
#pragma unroll
                for (int dt = 0; dt < 4; ++dt) Oa[dt][r] = 0.f;
            }

            for (int j = 0; j <= jmax; ++j) {
                const int k0 = j << 7;
                __syncthreads();   // prior tile's frag reads done before restage
#pragma unroll
                for (int r = 0; r < 4; ++r) {
                    const int i = w * 4 + r;
                    glds16(kbase + (size_t)(k0 + i * 8 + (l >> 3)) * RS2 + (((l & 7) ^ (l >> 3)) << 3),
                           &KT[i * 512 + l * 8]);
                }
#pragma unroll
                for (int r = 0; r < 4; ++r) {
                    const int i = w * 4 + r;
                    const int key = ((i & 3) << 2) + (l >> 4);
                    glds16(vbase + (size_t)(i * 4 + (l >> 4)) * Tn + k0 + (((l & 15) ^ key) << 3),
                           &VT[i * 512 + l * 8]);
                }
                __syncthreads();

                // S = Q~ K^T + (-16)  (exp2 domain, pre-scaled; static max folded in)
                ffrag s[8];
#pragma unroll
                for (int nt = 0; nt < 8; ++nt) {
                    bfrag ka = *(const bfrag*)&KT[(nt * 16 + nl) * 64 + (((lq) ^ (nl & 7)) << 3)];
                    bfrag kb = *(const bfrag*)&KT[(nt * 16 + nl) * 64 + (((4 + lq) ^ (nl & 7)) << 3)];
                    ffrag z;
#pragma unroll
                    for (int r = 0; r < 4; ++r) z[r] = -SMAX;
                    z = __builtin_amdgcn_mfma_f32_16x16x32_bf16(qf[0], ka, z, 0, 0, 0);
                    s[nt] = __builtin_amdgcn_mfma_f32_16x16x32_bf16(qf[1], kb, z, 0, 0, 0);
                }

                if (j == jmax) {   // tile containing the diagonal: causal mask
#pragma unroll
                    for (int nt = 0; nt < 8; ++nt) {
                        const int kc = k0 + nt * 16 + nl;
#pragma unroll
                        for (int r = 0; r < 4; ++r)
                            if (kc > rowb + lq * 4 + r) s[nt][r] = -INFINITY;
                    }
                }

                // static-max softmax: p = exp2(s); per-lane partial row sums
#pragma unroll
                for (int r = 0; r < 4; ++r) {
                    const int prow = lq * 4 + r;
                    float acc = 0.f;
#pragma unroll
                    for (int nt = 0; nt < 8; ++nt) {
                        const float pvv = __builtin_amdgcn_exp2f(s[nt][r]);
                        acc += pvv;
                        Ps[w][prow][nt * 16 + nl] = f2bf_fast(pvv);
                    }
                    l_i[r] += acc;
                }

                // PV (wave-private Ps; DS pipe in-order per wave)
#pragma unroll
                for (int cs = 0; cs < 4; ++cs) {
                    bfrag pf = *(const bfrag*)&Ps[w][nl][cs * 32 + lq * 8];
#pragma unroll
                    for (int dt = 0; dt < 4; ++dt) {
                        bfrag vf = *(const bfrag*)&VT[(dt * 16 + nl) * 128 + ((((cs << 2) + lq) ^ nl) << 3)];
                        Oa[dt] = __builtin_amdgcn_mfma_f32_16x16x32_bf16(pf, vf, Oa[dt], 0, 0, 0);
                    }
                }
            }

            // epilogue: reduce l across row, normalize, store
#pragma unroll
            for (int r = 0; r < 4; ++r) {
                const float lr = rowsum16(l_i[r]);
                const float inv = 1.f / lr;
                const int row = rowb + lq * 4 + r;
#pragma unroll
                for (int dt = 0; dt < 4; ++dt)
                    yb[(size_t)row * En + dt * 16 + nl] = f2bf(Oa[dt][r] * inv);
            }
        }
    }
}

extern "C" void kernel_launch(void* const* d_in, const int* in_sizes, int n_in,
                              void* d_out, int out_size, void* d_ws, size_t ws_size,
                              hipStream_t stream)
{
    const float* x      = (const float*)d_in[0];
    const float* W_qkv  = (const float*)d_in[1];
    const float* b_qkv  = (const float*)d_in[2];
    const float* W_proj = (const float*)d_in[3];
    const float* b_proj = (const float*)d_in[4];
    float* out = (float*)d_out;

    const int M = Bn * Tn;   // 8192
    char* ws = (char*)d_ws;
    unsigned short* xb   = (unsigned short*)ws; ws += (size_t)M * En * 2;
    unsigned short* Wqt  = (unsigned short*)ws; ws += (size_t)3 * En * En * 2;
    unsigned short* Wpt  = (unsigned short*)ws; ws += (size_t)En * En * 2;
    unsigned short* qkb  = (unsigned short*)ws; ws += (size_t)M * 2 * En * 2;   // Q|K
    unsigned short* vtg  = (unsigned short*)ws; ws += (size_t)M * En * 2;       // V^T per head
    unsigned short* yb   = (unsigned short*)ws;

    f2bf_vec<<<(M * En / 4 + 255) / 256, 256, 0, stream>>>(x, xb, M * En);
    transpose_f2bf<<<dim3(3 * En / 64, En / 64), 256, 0, stream>>>(W_qkv, Wqt, En, 3 * En);
    transpose_f2bf<<<dim3(En / 64, En / 64), 256, 0, stream>>>(W_proj, Wpt, En, En);

    gemm_nt_mfma<1, 1><<<dim3(3 * En / 128, M / 128), 256, 0, stream>>>(
        xb, Wqt, b_qkv, qkb, 2 * En, vtg, 2 * En, M, 3 * En, En, En);

    attn_mfma<<<dim3(512), 256, 0, stream>>>(qkb, vtg, yb);

    gemm_nt_mfma<0, 0><<<dim3(En / 128, M / 128), 256, 0, stream>>>(
        yb, Wpt, b_proj, out, En, nullptr, 1 << 30, M, En, En, 0);
}

// Round 8
// 274.144 us; speedup vs baseline: 1.5189x; 1.5189x over previous
//
#include <hip/hip_runtime.h>
#include <math.h>

#define Bn 4
#define Tn 2048
#define En 1024
#define Hn 16
#define Dn 64
#define RS2 (2 * En)
#define QSCALE 0.18033688f   // (1/sqrt(64)) * log2(e)  -> softmax in exp2 domain
#define SMAX 16.0f           // static softmax max (log2 domain); scores bounded << 16

typedef __attribute__((ext_vector_type(8))) short bfrag;   // 8 bf16 in 4 VGPRs
typedef __attribute__((ext_vector_type(4))) float ffrag;   // 4 fp32 acc

__device__ __forceinline__ unsigned short f2bf(float f) {
    union { float f; unsigned int u; } v; v.f = f;
    unsigned int r = v.u + 0x7fffu + ((v.u >> 16) & 1u);   // RNE
    return (unsigned short)(r >> 16);
}
__device__ __forceinline__ unsigned short f2bf_fast(float f) {  // positive, no NaN
    union { float f; unsigned int u; } v; v.f = f;
    return (unsigned short)((v.u + 0x8000u) >> 16);
}

__device__ __forceinline__ void glds16(const unsigned short* g, unsigned short* l) {
    __builtin_amdgcn_global_load_lds(
        (const __attribute__((address_space(1))) unsigned int*)g,
        (__attribute__((address_space(3))) unsigned int*)l, 16, 0, 0);
}

// ---- DPP 16-lane row sum ----
template <int CTRL>
__device__ __forceinline__ float dpp_add_step(float x) {
    int s = __builtin_amdgcn_update_dpp(0, __builtin_bit_cast(int, x), CTRL, 0xF, 0xF, true);
    return x + __builtin_bit_cast(float, s);
}
__device__ __forceinline__ float rowsum16(float x) {
    x = dpp_add_step<0xB1>(x);    // quad_perm xor1
    x = dpp_add_step<0x4E>(x);    // quad_perm xor2
    x = dpp_add_step<0x141>(x);   // row_half_mirror
    x = dpp_add_step<0x140>(x);   // row_mirror
    return x;
}

// ---------------- fp32 -> bf16 elementwise ----------------
__global__ __launch_bounds__(256) void f2bf_vec(const float* __restrict__ in,
                                                unsigned short* __restrict__ out, int n) {
    int i = (blockIdx.x * 256 + threadIdx.x) * 4;
    if (i >= n) return;
    float4 v = *(const float4*)(in + i);
    ushort4 o;
    o.x = f2bf(v.x); o.y = f2bf(v.y); o.z = f2bf(v.z); o.w = f2bf(v.w);
    *(ushort4*)(out + i) = o;
}

// ---------------- W[K][N] fp32 -> Wt[N][K] bf16 ----------------
__global__ __launch_bounds__(256) void transpose_f2bf(const float* __restrict__ W,
                                                      unsigned short* __restrict__ Wt,
                                                      int K, int N) {
    __shared__ float s[64][65];
    const int kt = blockIdx.y * 64, nt = blockIdx.x * 64;
    const int tx = threadIdx.x & 15, ty = threadIdx.x >> 4;
#pragma unroll
    for (int i = 0; i < 4; ++i) {
        float4 v = *(const float4*)&W[(size_t)(kt + ty + i * 16) * N + nt + tx * 4];
        s[ty + i * 16][tx * 4 + 0] = v.x;
        s[ty + i * 16][tx * 4 + 1] = v.y;
        s[ty + i * 16][tx * 4 + 2] = v.z;
        s[ty + i * 16][tx * 4 + 3] = v.w;
    }
    __syncthreads();
#pragma unroll
    for (int i = 0; i < 4; ++i) {
        const int n = ty + i * 16;
        ushort4 o;
        o.x = f2bf(s[tx * 4 + 0][n]);
        o.y = f2bf(s[tx * 4 + 1][n]);
        o.z = f2bf(s[tx * 4 + 2][n]);
        o.w = f2bf(s[tx * 4 + 3][n]);
        *(ushort4*)&Wt[(size_t)(nt + n) * K + kt + tx * 4] = o;
    }
}

// ---------------- NT bf16 MFMA GEMM, BK=64 full-line staging ----------------
// C = A[M,K] @ Bt[N,K]^T + bias. 128x128 tile, BK=64, 4 waves (2x2 of 64x64).
// A/B tiles in LDS as 128 rows x 128B with chunk-XOR swizzle (pos = chunk ^
// (row&7)); each glds16 covers 8 rows x 128B = full L2 lines (vs 16 half-line
// segments in the BK=32 cell layout). 16 iters, 32 MFMA : 16 ds_read_b128 :
// 8 glds per wave per iter. Grid is 1D with an XCD-aware swizzle: 8
// consecutive y-slabs per XCD so A re-reads stay XCD-L2-local.
template <int OUT_BF16, int VSPLIT>
__global__ __launch_bounds__(256) void gemm_nt_mfma(
    const unsigned short* __restrict__ A, const unsigned short* __restrict__ Bt,
    const float* __restrict__ bias, void* __restrict__ Cv, int ldc,
    unsigned short* __restrict__ vt, int vstart,
    int M, int N, int K, int qcols, int gx)
{
    __shared__ __attribute__((aligned(16))) unsigned short As[128 * 64];
    __shared__ __attribute__((aligned(16))) unsigned short Bs[128 * 64];

    const int t = threadIdx.x;
    const int w = t >> 6, l = t & 63;
    const int wmt = (w & 1) * 4, wnt = (w >> 1) * 4;
    const int nl = l & 15, lq = l >> 4;
    const int r8 = l >> 3, c8 = l & 7;        // staging: row-in-group / chunk
    const int cs8 = c8 ^ r8;                  // swizzled source chunk

    // XCD-aware flat -> tile mapping (xcd = flat % 8 heuristic)
    const int flat = blockIdx.x;
    const int xcd = flat & 7;
    const int g = flat >> 3;
    const int bx = g % gx;
    const int by = xcd * 8 + g / gx;          // M/128 == 64 -> 8 slabs per XCD
    const int m0 = by * 128, n0 = bx * 128;

    ffrag acc[4][4];
#pragma unroll
    for (int i = 0; i < 4; ++i)
#pragma unroll
        for (int j = 0; j < 4; ++j)
#pragma unroll
            for (int r = 0; r < 4; ++r) acc[i][j][r] = 0.f;

    const unsigned short* Ag = A  + (size_t)(m0 + r8) * K + cs8 * 8;
    const unsigned short* Bg = Bt + (size_t)(n0 + r8) * K + cs8 * 8;

    const int iters = K >> 6;   // 16
#pragma unroll 1
    for (int it = 0; it < iters; ++it) {
        const int k0 = it << 6;
        __syncthreads();   // prior iter's frag reads done before restage
#pragma unroll
        for (int r = 0; r < 4; ++r) {
            const int i = w * 4 + r;   // 8-row group 0..15
            glds16(Ag + (size_t)(i * 8) * K + k0, &As[i * 512 + l * 8]);
            glds16(Bg + (size_t)(i * 8) * K + k0, &Bs[i * 512 + l * 8]);
        }
        __syncthreads();
#pragma unroll
        for (int ks = 0; ks < 2; ++ks) {
            bfrag af[4], bf[4];
#pragma unroll
            for (int i = 0; i < 4; ++i) {
                const int pos = ((ks * 4 + lq) ^ (nl & 7)) << 3;
                af[i] = *(const bfrag*)&As[((wmt + i) * 16 + nl) * 64 + pos];
                bf[i] = *(const bfrag*)&Bs[((wnt + i) * 16 + nl) * 64 + pos];
            }
#pragma unroll
            for (int i = 0; i < 4; ++i)
#pragma unroll
                for (int j = 0; j < 4; ++j)
                    acc[i][j] = __builtin_amdgcn_mfma_f32_16x16x32_bf16(af[i], bf[j], acc[i][j], 0, 0, 0);
        }
    }

    const int orow = lq * 4, ocol = nl;
#pragma unroll
    for (int i = 0; i < 4; ++i) {
        const int gm = m0 + (wmt + i) * 16 + orow;
#pragma unroll
        for (int j = 0; j < 4; ++j) {
            const int gn = n0 + (wnt + j) * 16 + ocol;
            const float bs = bias[gn];
            if (VSPLIT && gn >= vstart) {
                const int vc = gn - vstart;
                const int b  = gm / Tn;
                const int tt = gm - b * Tn;
                ushort4 o;
                o.x = f2bf(acc[i][j][0] + bs);
                o.y = f2bf(acc[i][j][1] + bs);
                o.z = f2bf(acc[i][j][2] + bs);
                o.w = f2bf(acc[i][j][3] + bs);
                *(ushort4*)&vt[(size_t)(b * Hn * Dn + vc) * Tn + tt] = o;
            } else {
                const float sc = (qcols && gn < qcols) ? QSCALE : 1.f;
#pragma unroll
                for (int r = 0; r < 4; ++r) {
                    const float vv = (acc[i][j][r] + bs) * sc;
                    if (OUT_BF16)
                        ((unsigned short*)Cv)[(size_t)(gm + r) * ldc + gn] = f2bf(vv);
                    else
                        ((float*)Cv)[(size_t)(gm + r) * ldc + gn] = vv;
                }
            }
        }
    }
}

// ---------------- MFMA flash attention (round-5 structure, unchanged) ----------------
__global__ __launch_bounds__(256) void attn_mfma(
    const unsigned short* __restrict__ qkv,   // [B*T][2E]  Q|K, Q pre-scaled
    const unsigned short* __restrict__ vtg,   // [B*H*D][T] V transposed
    unsigned short* __restrict__ yattn)       // [B*T][E]
{
    __shared__ __attribute__((aligned(16))) unsigned short KT[128 * 64];
    __shared__ __attribute__((aligned(16))) unsigned short VT[64 * 128];
    __shared__ __attribute__((aligned(16))) unsigned short Ps[4][16][136];

    const int t = threadIdx.x;
    const int w = t >> 6, l = t & 63;
    const int nl = l & 15, lq = l >> 4;
    const int flat = blockIdx.x;
    const int bh = flat & 63;
    const int qp = flat >> 6;         // 0..7
    const int b = bh >> 4, h = bh & 15;

    const unsigned short* qbase = qkv + (size_t)(b * Tn) * RS2 + h * Dn;
    const unsigned short* kbase = qbase + En;
    const unsigned short* vbase = vtg + (size_t)(bh * Dn) * Tn;
    unsigned short* yb = yattn + (size_t)(b * Tn) * En + h * Dn;

#pragma unroll 1
    for (int half = 0; half < 2; ++half) {
        const int p = qp + half * 8;          // pair 0..15
#pragma unroll 1
        for (int phase = 0; phase < 2; ++phase) {
            const int qt = phase ? (31 - p) : p;
            const int rowb = qt * 64 + w * 16;
            const int jmax = qt >> 1;

            bfrag qf[2];
#pragma unroll
            for (int ks = 0; ks < 2; ++ks)
                qf[ks] = *(const bfrag*)(qbase + (size_t)(rowb + nl) * RS2 + ks * 32 + lq * 8);

            ffrag Oa[4];
            float l_i[4];
#pragma unroll
            for (int r = 0; r < 4; ++r) {
                l_i[r] = 0.f;
#pragma unroll
                for (int dt = 0; dt < 4; ++dt) Oa[dt][r] = 0.f;
            }

            for (int j = 0; j <= jmax; ++j) {
                const int k0 = j << 7;
                __syncthreads();   // prior tile's frag reads done before restage
#pragma unroll
                for (int r = 0; r < 4; ++r) {
                    const int i = w * 4 + r;
                    glds16(kbase + (size_t)(k0 + i * 8 + (l >> 3)) * RS2 + (((l & 7) ^ (l >> 3)) << 3),
                           &KT[i * 512 + l * 8]);
                }
#pragma unroll
                for (int r = 0; r < 4; ++r) {
                    const int i = w * 4 + r;
                    const int key = ((i & 3) << 2) + (l >> 4);
                    glds16(vbase + (size_t)(i * 4 + (l >> 4)) * Tn + k0 + (((l & 15) ^ key) << 3),
                           &VT[i * 512 + l * 8]);
                }
                __syncthreads();

                // S = Q~ K^T + (-16)  (exp2 domain, pre-scaled; static max folded in)
                ffrag s[8];
#pragma unroll
                for (int nt = 0; nt < 8; ++nt) {
                    bfrag ka = *(const bfrag*)&KT[(nt * 16 + nl) * 64 + (((lq) ^ (nl & 7)) << 3)];
                    bfrag kb = *(const bfrag*)&KT[(nt * 16 + nl) * 64 + (((4 + lq) ^ (nl & 7)) << 3)];
                    ffrag z;
#pragma unroll
                    for (int r = 0; r < 4; ++r) z[r] = -SMAX;
                    z = __builtin_amdgcn_mfma_f32_16x16x32_bf16(qf[0], ka, z, 0, 0, 0);
                    s[nt] = __builtin_amdgcn_mfma_f32_16x16x32_bf16(qf[1], kb, z, 0, 0, 0);
                }

                if (j == jmax) {   // tile containing the diagonal: causal mask
#pragma unroll
                    for (int nt = 0; nt < 8; ++nt) {
                        const int kc = k0 + nt * 16 + nl;
#pragma unroll
                        for (int r = 0; r < 4; ++r)
                            if (kc > rowb + lq * 4 + r) s[nt][r] = -INFINITY;
                    }
                }

                // static-max softmax: p = exp2(s); per-lane partial row sums
#pragma unroll
                for (int r = 0; r < 4; ++r) {
                    const int prow = lq * 4 + r;
                    float acc = 0.f;
#pragma unroll
                    for (int nt = 0; nt < 8; ++nt) {
                        const float pvv = __builtin_amdgcn_exp2f(s[nt][r]);
                        acc += pvv;
                        Ps[w][prow][nt * 16 + nl] = f2bf_fast(pvv);
                    }
                    l_i[r] += acc;
                }

                // PV (wave-private Ps; DS pipe in-order per wave)
#pragma unroll
                for (int cs = 0; cs < 4; ++cs) {
                    bfrag pf = *(const bfrag*)&Ps[w][nl][cs * 32 + lq * 8];
#pragma unroll
                    for (int dt = 0; dt < 4; ++dt) {
                        bfrag vf = *(const bfrag*)&VT[(dt * 16 + nl) * 128 + ((((cs << 2) + lq) ^ nl) << 3)];
                        Oa[dt] = __builtin_amdgcn_mfma_f32_16x16x32_bf16(pf, vf, Oa[dt], 0, 0, 0);
                    }
                }
            }

            // epilogue: reduce l across row, normalize, store
#pragma unroll
            for (int r = 0; r < 4; ++r) {
                const float lr = rowsum16(l_i[r]);
                const float inv = 1.f / lr;
                const int row = rowb + lq * 4 + r;
#pragma unroll
                for (int dt = 0; dt < 4; ++dt)
                    yb[(size_t)row * En + dt * 16 + nl] = f2bf(Oa[dt][r] * inv);
            }
        }
    }
}

extern "C" void kernel_launch(void* const* d_in, const int* in_sizes, int n_in,
                              void* d_out, int out_size, void* d_ws, size_t ws_size,
                              hipStream_t stream)
{
    const float* x      = (const float*)d_in[0];
    const float* W_qkv  = (const float*)d_in[1];
    const float* b_qkv  = (const float*)d_in[2];
    const float* W_proj = (const float*)d_in[3];
    const float* b_proj = (const float*)d_in[4];
    float* out = (float*)d_out;

    const int M = Bn * Tn;   // 8192
    char* ws = (char*)d_ws;
    unsigned short* xb   = (unsigned short*)ws; ws += (size_t)M * En * 2;
    unsigned short* Wqt  = (unsigned short*)ws; ws += (size_t)3 * En * En * 2;
    unsigned short* Wpt  = (unsigned short*)ws; ws += (size_t)En * En * 2;
    unsigned short* qkb  = (unsigned short*)ws; ws += (size_t)M * 2 * En * 2;   // Q|K
    unsigned short* vtg  = (unsigned short*)ws; ws += (size_t)M * En * 2;       // V^T per head
    unsigned short* yb   = (unsigned short*)ws;

    f2bf_vec<<<(M * En / 4 + 255) / 256, 256, 0, stream>>>(x, xb, M * En);
    transpose_f2bf<<<dim3(3 * En / 64, En / 64), 256, 0, stream>>>(W_qkv, Wqt, En, 3 * En);
    transpose_f2bf<<<dim3(En / 64, En / 64), 256, 0, stream>>>(W_proj, Wpt, En, En);

    gemm_nt_mfma<1, 1><<<dim3((3 * En / 128) * (M / 128)), 256, 0, stream>>>(
        xb, Wqt, b_qkv, qkb, 2 * En, vtg, 2 * En, M, 3 * En, En, En, 3 * En / 128);

    attn_mfma<<<dim3(512), 256, 0, stream>>>(qkb, vtg, yb);

    gemm_nt_mfma<0, 0><<<dim3((En / 128) * (M / 128)), 256, 0, stream>>>(
        yb, Wpt, b_proj, out, En, nullptr, 1 << 30, M, En, En, 0, En / 128);
}